// Round 1
// baseline (154.005 us; speedup 1.0000x reference)
//
#include <hip/hip_runtime.h>
#include <stdint.h>

#define BB 4
#define SS 2048
#define DD 512
#define NTQ 32            // S/64 q-tiles per batch
#define NEG_BIG -1e30f

typedef __attribute__((ext_vector_type(4))) float f32x4;
typedef __attribute__((ext_vector_type(8))) short bf16x8;

__device__ __forceinline__ ushort f2bf(float x) {
  uint32_t u = __float_as_uint(x);
  u += 0x7FFFu + ((u >> 16) & 1u);     // RNE to bf16
  return (ushort)(u >> 16);
}
__device__ __forceinline__ float bf2f(ushort h) {
  return __uint_as_float(((uint32_t)h) << 16);
}

// Causal flash attention, fp32 in/out.
// - swapped MFMA: S^T = K*Q^T (A=K rows from LDS, B=Q rows from regs)
// - 3-pass split-bf16 QK^T for fp32-grade logits
// - PV: O^T = V^T*P^T, V transposed in LDS, one 16x16x32 MFMA per d-tile per kv-pair
// - block = 4 waves x 16 q-rows = 64 q-rows, KV tiles of 16 processed in pairs
// - kv-split R across blocks; partials (O',m,l) to workspace; combine kernel merges
__global__ __launch_bounds__(256, 1)
void attn_kernel(const float* __restrict__ Kg, const float* __restrict__ Qg,
                 const float* __restrict__ Vg, float* __restrict__ Opart,
                 float* __restrict__ MLp, float* __restrict__ Out,
                 int R, int direct)
{
  __shared__ char smem[65536];
  // [0,16384)      K_hi [16][512] bf16, XOR-swizzled (row&7)<<4
  // [16384,32768)  K_lo [16][512]
  // [32768,65536)  VT[2][512][16] bf16 (V transposed), bit-4 swizzle by (d>>2)&1
  float* otr = (float*)smem;             // epilogue reuse: [64][132] f32

  const int tid = threadIdx.x;
  const int ln  = tid & 63;
  const int w   = tid >> 6;
  const int m   = ln & 15;   // lane row-in-16
  const int g   = ln >> 4;   // lane group 0..3

  const int u    = blockIdx.x;
  const int tIdx = u / (BB * R);
  const int t    = (NTQ - 1) - tIdx;     // longest blocks dispatched first
  const int rem  = u % (BB * R);
  const int b    = rem / R;
  const int r    = rem % R;

  const int T16 = 4 * (t + 1);                        // kv 16-tiles in causal range
  const int C   = 2 * ((T16 + 2 * R - 1) / (2 * R));  // even chunk size
  const int j0  = r * C;
  const int j1  = min(j0 + C, T16);

  const int qrow = t * 64 + w * 16 + m;  // this lane's q row

  // ---- Q fragments (hi/lo bf16) into registers: B[k][n]=Q[q=m][k]
  bf16x8 qhi[16], qlo[16];
  {
    const float* qp = Qg + ((size_t)(b * SS + qrow)) * DD + g * 8;
    #pragma unroll
    for (int ks = 0; ks < 16; ++ks) {
      float4 a = *(const float4*)(qp + ks * 32);
      float4 c = *(const float4*)(qp + ks * 32 + 4);
      float xv[8] = {a.x, a.y, a.z, a.w, c.x, c.y, c.z, c.w};
      bf16x8 hv, lv;
      #pragma unroll
      for (int e = 0; e < 8; ++e) {
        ushort hh = f2bf(xv[e]);
        hv[e] = (short)hh;
        lv[e] = (short)f2bf(xv[e] - bf2f(hh));
      }
      qhi[ks] = hv; qlo[ks] = lv;
    }
  }

  f32x4 acc[32];
  {
    f32x4 z = {0.f, 0.f, 0.f, 0.f};
    #pragma unroll
    for (int i = 0; i < 32; ++i) acc[i] = z;
  }
  float mst = NEG_BIG, lst = 0.f;
  float pA0 = 0, pA1 = 0, pA2 = 0, pA3 = 0, scA = 1.f;

  for (int j = j0; j < j1; ++j) {
    const int kv0 = j * 16;
    const int par = (j - j0) & 1;

    // ---- stage K tile (hi/lo bf16) -----------------------------------------
    #pragma unroll
    for (int i = 0; i < 8; ++i) {
      int chunk = tid + 256 * i;          // 2048 float4 chunks = 16x512 fp32
      int rr = chunk >> 7;
      int cc = (chunk & 127) << 2;
      float4 a = *(const float4*)(Kg + ((size_t)(b * SS + kv0 + rr)) * DD + cc);
      ushort h0 = f2bf(a.x), h1 = f2bf(a.y), h2 = f2bf(a.z), h3 = f2bf(a.w);
      uint32_t hA = (uint32_t)h0 | ((uint32_t)h1 << 16);
      uint32_t hB = (uint32_t)h2 | ((uint32_t)h3 << 16);
      uint32_t lA = (uint32_t)f2bf(a.x - bf2f(h0)) | ((uint32_t)f2bf(a.y - bf2f(h1)) << 16);
      uint32_t lB = (uint32_t)f2bf(a.z - bf2f(h2)) | ((uint32_t)f2bf(a.w - bf2f(h3)) << 16);
      int off = rr * 1024 + ((cc * 2) ^ ((rr & 7) << 4));
      *(uint2*)(smem + off)         = make_uint2(hA, hB);
      *(uint2*)(smem + 16384 + off) = make_uint2(lA, lB);
    }
    // ---- stage V transposed ------------------------------------------------
    #pragma unroll
    for (int half = 0; half < 2; ++half) {
      int d = tid + 256 * half;
      const float* vp = Vg + ((size_t)(b * SS + kv0)) * DD + d;
      int vbase = 32768 + par * 16384 + d * 32;
      int swz = ((d >> 2) & 1) << 4;
      #pragma unroll
      for (int kq = 0; kq < 4; ++kq) {
        float v0 = vp[(kq * 4 + 0) * DD], v1 = vp[(kq * 4 + 1) * DD];
        float v2 = vp[(kq * 4 + 2) * DD], v3 = vp[(kq * 4 + 3) * DD];
        uint32_t pa = (uint32_t)f2bf(v0) | ((uint32_t)f2bf(v1) << 16);
        uint32_t pb = (uint32_t)f2bf(v2) | ((uint32_t)f2bf(v3) << 16);
        *(uint2*)(smem + vbase + ((kq * 8) ^ swz)) = make_uint2(pa, pb);
      }
    }
    __syncthreads();

    // ---- QK^T: S^T[16kv][16q], 3-pass split ---------------------------------
    f32x4 s = {0.f, 0.f, 0.f, 0.f};
    {
      const char* krow = smem + m * 1024;
      const int rsw = (m & 7) << 4;
      #pragma unroll
      for (int ks = 0; ks < 16; ++ks) {
        int off = (ks * 64 + g * 16) ^ rsw;
        bf16x8 kh = *(const bf16x8*)(krow + off);
        bf16x8 kl = *(const bf16x8*)(krow + 16384 + off);
        s = __builtin_amdgcn_mfma_f32_16x16x32_bf16(kh, qhi[ks], s, 0, 0, 0);
        s = __builtin_amdgcn_mfma_f32_16x16x32_bf16(kl, qhi[ks], s, 0, 0, 0);
        s = __builtin_amdgcn_mfma_f32_16x16x32_bf16(kh, qlo[ks], s, 0, 0, 0);
      }
    }

    // ---- online softmax: lane holds S^T[kv0+4g+r][qrow] ---------------------
    float sv0 = (kv0 + 4 * g + 0 <= qrow) ? s[0] : NEG_BIG;
    float sv1 = (kv0 + 4 * g + 1 <= qrow) ? s[1] : NEG_BIG;
    float sv2 = (kv0 + 4 * g + 2 <= qrow) ? s[2] : NEG_BIG;
    float sv3 = (kv0 + 4 * g + 3 <= qrow) ? s[3] : NEG_BIG;
    float tm = fmaxf(fmaxf(sv0, sv1), fmaxf(sv2, sv3));
    tm = fmaxf(tm, __shfl_xor(tm, 16));
    tm = fmaxf(tm, __shfl_xor(tm, 32));
    float mnew = fmaxf(mst, tm);
    float sc = __expf(mst - mnew);
    float p0 = (kv0 + 4 * g + 0 <= qrow) ? __expf(sv0 - mnew) : 0.f;
    float p1 = (kv0 + 4 * g + 1 <= qrow) ? __expf(sv1 - mnew) : 0.f;
    float p2 = (kv0 + 4 * g + 2 <= qrow) ? __expf(sv2 - mnew) : 0.f;
    float p3 = (kv0 + 4 * g + 3 <= qrow) ? __expf(sv3 - mnew) : 0.f;
    float rs = p0 + p1 + p2 + p3;
    rs += __shfl_xor(rs, 16);
    rs += __shfl_xor(rs, 32);
    lst = lst * sc + rs;
    mst = mnew;

    if (par == 0) {
      scA = sc; pA0 = p0; pA1 = p1; pA2 = p2; pA3 = p3;
    } else {
      float osc = scA * sc;                 // rescale O across the pair
      pA0 *= sc; pA1 *= sc; pA2 *= sc; pA3 *= sc;
      uint32_t uA0 = (uint32_t)f2bf(pA0) | ((uint32_t)f2bf(pA1) << 16);
      uint32_t uA1 = (uint32_t)f2bf(pA2) | ((uint32_t)f2bf(pA3) << 16);
      uint32_t uB0 = (uint32_t)f2bf(p0)  | ((uint32_t)f2bf(p1)  << 16);
      uint32_t uB1 = (uint32_t)f2bf(p2)  | ((uint32_t)f2bf(p3)  << 16);
      // build PV B-frag: VGPR pp holds kv pair k'=8g+2pp (tile = g>>1)
      union { int4 i4; bf16x8 b8; } pf;
      #pragma unroll
      for (int pp = 0; pp < 4; ++pp) {
        int gc  = 2 * (g & 1) + (pp >> 1);
        int src = m + 16 * gc;
        int va = __shfl((int)((pp & 1) ? uA1 : uA0), src);
        int vb = __shfl((int)((pp & 1) ? uB1 : uB0), src);
        int vsel = (g >> 1) ? vb : va;
        if      (pp == 0) pf.i4.x = vsel;
        else if (pp == 1) pf.i4.y = vsel;
        else if (pp == 2) pf.i4.z = vsel;
        else              pf.i4.w = vsel;
      }
      #pragma unroll
      for (int i = 0; i < 32; ++i) {
        acc[i][0] *= osc; acc[i][1] *= osc; acc[i][2] *= osc; acc[i][3] *= osc;
      }
      const int vswz = (g & 1) << 4;
      #pragma unroll
      for (int dt = 0; dt < 32; ++dt) {
        int d = dt * 16 + m;
        int off = 32768 + (g >> 1) * 16384 + d * 32 + (vswz ^ (((d >> 2) & 1) << 4));
        bf16x8 vf = *(const bf16x8*)(smem + off);
        acc[dt] = __builtin_amdgcn_mfma_f32_16x16x32_bf16(vf, pf.b8, acc[dt], 0, 0, 0);
      }
    }
    __syncthreads();
  }

  // ---- epilogue: (m,l) + O' (or direct normalized output) -------------------
  if (!direct && ln < 16) {
    float* mlp = MLp + ((size_t)u * 64 + w * 16 + m) * 2;
    mlp[0] = mst; mlp[1] = lst;
  }
  float norm = direct ? (1.0f / lst) : 1.f;   // direct: every row has >=1 valid kv

  #pragma unroll
  for (int cc = 0; cc < 4; ++cc) {
    __syncthreads();
    #pragma unroll
    for (int dd = 0; dd < 8; ++dd) {
      int dt = cc * 8 + dd;
      #pragma unroll
      for (int rr = 0; rr < 4; ++rr) {
        otr[(w * 16 + m) * 132 + dd * 16 + 4 * g + rr] = acc[dt][rr] * norm;
      }
    }
    __syncthreads();
    #pragma unroll
    for (int ii = 0; ii < 8; ++ii) {
      int idx = tid + 256 * ii;
      int row = idx >> 5;
      int c4  = (idx & 31) << 2;
      float4 v4 = *(const float4*)(otr + row * 132 + c4);
      if (direct) {
        int qg2 = t * 64 + row;
        *(float4*)(Out + ((size_t)(b * SS + qg2)) * 1024 + 512 + cc * 128 + c4) = v4;
      } else {
        *(float4*)(Opart + ((size_t)u * 64 + row) * 512 + cc * 128 + c4) = v4;
      }
    }
  }
}

__global__ __launch_bounds__(256)
void combine_kernel(const float* __restrict__ Opart, const float* __restrict__ MLp,
                    const float* __restrict__ orig, float* __restrict__ Out, int R)
{
  int gid = blockIdx.x * 256 + threadIdx.x;
  int row = gid >> 7;
  int c4  = (gid & 127) << 2;
  int b = row >> 11;
  int s = row & 2047;
  int t = s >> 6;
  int qloc = s & 63;

  // copy original into out[..., 0:512]
  *(float4*)(Out + (size_t)row * 1024 + c4) = *(const float4*)(orig + (size_t)row * 512 + c4);

  int ubase = (NTQ - 1 - t) * (BB * R) + b * R;
  float mr[4] = {NEG_BIG, NEG_BIG, NEG_BIG, NEG_BIG};
  float lr[4] = {0.f, 0.f, 0.f, 0.f};
  #pragma unroll
  for (int rr = 0; rr < 4; ++rr) {
    if (rr < R) {
      const float* p = MLp + ((size_t)(ubase + rr) * 64 + qloc) * 2;
      mr[rr] = p[0]; lr[rr] = p[1];
    }
  }
  float M = fmaxf(fmaxf(mr[0], mr[1]), fmaxf(mr[2], mr[3]));
  float L = 0.f, a0 = 0.f, a1 = 0.f, a2 = 0.f, a3 = 0.f;
  #pragma unroll
  for (int rr = 0; rr < 4; ++rr) {
    if (rr < R && mr[rr] > -5e29f) {     // skip empty chunks (never touch their O')
      float wgt = __expf(mr[rr] - M);
      L += wgt * lr[rr];
      const float* op = Opart + ((size_t)(ubase + rr) * 64 + qloc) * 512 + c4;
      a0 += wgt * op[0]; a1 += wgt * op[1]; a2 += wgt * op[2]; a3 += wgt * op[3];
    }
  }
  float inv = 1.0f / L;
  float4 r4; r4.x = a0 * inv; r4.y = a1 * inv; r4.z = a2 * inv; r4.w = a3 * inv;
  *(float4*)(Out + (size_t)row * 1024 + 512 + c4) = r4;
}

__global__ __launch_bounds__(256)
void copy_orig(const float* __restrict__ orig, float* __restrict__ Out)
{
  int gid = blockIdx.x * 256 + threadIdx.x;
  int row = gid >> 7;
  int c4  = (gid & 127) << 2;
  *(float4*)(Out + (size_t)row * 1024 + c4) = *(const float4*)(orig + (size_t)row * 512 + c4);
}

extern "C" void kernel_launch(void* const* d_in, const int* in_sizes, int n_in,
                              void* d_out, int out_size, void* d_ws, size_t ws_size,
                              hipStream_t stream)
{
  (void)in_sizes; (void)n_in; (void)out_size;
  const float* keys     = (const float*)d_in[0];
  const float* queries  = (const float*)d_in[1];
  const float* values   = (const float*)d_in[2];
  const float* original = (const float*)d_in[3];
  float* out = (float*)d_out;

  const size_t perUnit = (size_t)64 * 512 * 4 + (size_t)64 * 8;  // O' + (m,l) per unit
  int R = 1;
  if      (ws_size >= (size_t)(NTQ * BB * 4) * perUnit) R = 4;
  else if (ws_size >= (size_t)(NTQ * BB * 2) * perUnit) R = 2;

  const int NU = NTQ * BB * R;
  float* Opart = (float*)d_ws;
  float* MLp   = (float*)((char*)d_ws + (size_t)NU * 64 * 512 * 4);
  const int direct = (R == 1) ? 1 : 0;

  hipLaunchKernelGGL(attn_kernel, dim3(NU), dim3(256), 0, stream,
                     keys, queries, values, Opart, MLp, out, R, direct);

  const int cgrid = (BB * SS * 128) / 256;   // 4096 blocks
  if (!direct)
    hipLaunchKernelGGL(combine_kernel, dim3(cgrid), dim3(256), 0, stream,
                       Opart, MLp, original, out, R);
  else
    hipLaunchKernelGGL(copy_orig, dim3(cgrid), dim3(256), 0, stream, original, out);
}